// Round 5
// baseline (3854.556 us; speedup 1.0000x reference)
//
#include <hip/hip_runtime.h>
#include <stdint.h>

// ---- frozen correctness (validated R3/R4: absmax 0.0) ----
// threefry partitionable (0,i), bits = out0^out1; Cephes log no-FMA, contract off.

static constexpr uint32_t BB = 32;
static constexpr uint32_t NN = 524288;      // 2^19
static constexpr uint32_t KK = 52429;       // max(1, round(0.1*N))
static constexpr uint32_t W = 64;           // workgroups per row (full passes)
static constexpr uint32_t CHUNK = NN / W;   // 8192 elements per WG
static constexpr uint32_t CAP = 65536;      // candidate cap per row (avg ~13-26K, 50+ sigma margin)
static constexpr uint32_t SELCAP = 512;     // boundary-tie selection cap per row
static constexpr uint32_t HSLOT = BB * 2048;             // u32 per hist slot
// ws layout: h0 | h3 | st1 | st2 | ccnt1 | ccnt2 | sel1 | sel2 | cand
static constexpr size_t MEMSET_BYTES = (size_t)(2 * HSLOT + 2 * BB * 8 + 2 * BB) * 4u;

// ---------------- XLA CPU f32 log (Cephes/Eigen-3.3, no FMA) ----------------
__device__ __forceinline__ float xla_logf(float xin) {
#pragma clang fp contract(off)
  float x = fmaxf(xin, __uint_as_float(0x00800000u));
  uint32_t bits = __float_as_uint(x);
  float e = (float)((int)(bits >> 23) - 126);
  x = __uint_as_float((bits & 0x807fffffu) | 0x3f000000u);
  bool mlt = x < 0.707106781186547524f;
  float tmp = mlt ? x : 0.0f;
  x = x - 1.0f;
  e = e - (mlt ? 1.0f : 0.0f);
  x = x + tmp;
  float x2 = x * x;
  float x3 = x2 * x;
  float y, y1, y2;
  y  = 7.0376836292E-2f * x + -1.1514610310E-1f;
  y1 = -1.2420140846E-1f * x + 1.4249322787E-1f;
  y2 = 2.0000714765E-1f * x + -2.4999993993E-1f;
  y  = y * x + 1.1676998740E-1f;
  y1 = y1 * x + -1.6668057665E-1f;
  y2 = y2 * x + 3.3333331174E-1f;
  y  = y * x3 + y1;
  y  = y * x3 + y2;
  y  = y * x3;
  y1 = e * -2.12194440e-4f;
  tmp = x2 * 0.5f;
  y = y + y1;
  x = x - tmp;
  y2 = e * 0.693359375f;
  x = x + y;
  x = x + y2;
  return x;
}

__device__ __forceinline__ float c_top_val()  { return xla_logf((float)((1.0 - 0.1) / 52429.0)); }
__device__ __forceinline__ float c_rand_val() { return xla_logf((float)(0.1 / 471859.0)); }

// ---------------- threefry-2x32, key=(0,42), out0^out1 ----------------
__device__ __forceinline__ uint32_t tf_bits(uint32_t i) {
  const uint32_t ks0 = 0u, ks1 = 42u, ks2 = 0x1BD11BDAu ^ 42u;
  uint32_t x0 = 0u + ks0;
  uint32_t x1 = i + ks1;
#define TFR(r) { x0 += x1; x1 = (x1 << (r)) | (x1 >> (32 - (r))); x1 ^= x0; }
  TFR(13) TFR(15) TFR(26) TFR(6)
  x0 += ks1; x1 += ks2 + 1u;
  TFR(17) TFR(29) TFR(16) TFR(24)
  x0 += ks2; x1 += ks0 + 2u;
  TFR(13) TFR(15) TFR(26) TFR(6)
  x0 += ks0; x1 += ks1 + 3u;
  TFR(17) TFR(29) TFR(16) TFR(24)
  x0 += ks1; x1 += ks2 + 4u;
  TFR(13) TFR(15) TFR(26) TFR(6)
  x0 += ks2; x1 += ks0 + 5u;
#undef TFR
  return x0 ^ x1;
}

__device__ __forceinline__ float gumbel_at(uint32_t i) {
  uint32_t b = tf_bits(i);
  float u = __uint_as_float((b >> 9) | 0x3f800000u) - 1.0f;
  u = fmaxf(u, 1.17549435e-38f);
  float nl = -xla_logf(u);
  return -xla_logf(nl);
}

__device__ __forceinline__ uint32_t key_x(float v) { return __float_as_uint(v) & 0x7fffffffu; }
__device__ __forceinline__ uint32_t key_s(float v) {
  uint32_t b = __float_as_uint(v);
  return (b & 0x80000000u) ? ~b : (b | 0x80000000u);
}

// per-row state (8 u32): [0]=p0 prefix(11b) [1]=cnt_gt_prefix [2]=thr [4]=m

// ---- pass-0 histogram of key_x top-11 bits ----
__global__ void __launch_bounds__(256)
k_hist0(const float* __restrict__ src, uint32_t* __restrict__ hist) {
  __shared__ uint32_t lh[2048];
  uint32_t row = blockIdx.y;
  for (uint32_t b = threadIdx.x; b < 2048; b += 256) lh[b] = 0u;
  __syncthreads();
  const float4* p = (const float4*)(src + (size_t)row * NN + (size_t)blockIdx.x * CHUNK);
  for (uint32_t j = threadIdx.x; j < CHUNK / 4; j += 256) {
    float4 v = p[j];
    float vv[4] = {v.x, v.y, v.z, v.w};
#pragma unroll
    for (int e = 0; e < 4; ++e) atomicAdd(&lh[key_x(vv[e]) >> 21], 1u);
  }
  __syncthreads();
  uint32_t* gh = hist + row * 2048;
  for (uint32_t b = threadIdx.x; b < 2048; b += 256) {
    uint32_t v = lh[b];
    if (v) atomicAdd(&gh[b], v);
  }
}

// ---- find 11-bit prefix bin containing the k-th largest ----
__global__ void __launch_bounds__(256)
k_scan0(const uint32_t* __restrict__ hist, uint32_t* __restrict__ st) {
  __shared__ uint32_t csum[256];
  int row = blockIdx.x;
  const uint32_t* h = hist + row * 2048;
  int t = threadIdx.x;
  uint32_t s = 0;
  for (int j = 0; j < 8; ++j) s += h[t * 8 + j];
  csum[t] = s;
  __syncthreads();
  if (t == 0) {
    uint32_t acc = 0, bin = 0;
    for (int c = 255; c >= 0; --c) {
      if (acc + csum[c] >= KK) {
        for (int b2 = c * 8 + 7; b2 >= c * 8; --b2) {
          uint32_t hv = h[b2];
          if (acc + hv >= KK) { bin = (uint32_t)b2; break; }
          acc += hv;
        }
        break;
      }
      acc += csum[c];
    }
    st[row * 8 + 0] = bin;
    st[row * 8 + 1] = acc;   // strictly greater than prefix bin
  }
}

// ---- collect columns whose key matches the 11-bit prefix ----
template <int SRC>
__global__ void __launch_bounds__(256)
k_candcoll(const float* __restrict__ src, const uint32_t* __restrict__ st,
           uint32_t* __restrict__ cand, uint32_t* __restrict__ ccnt) {
  uint32_t row = blockIdx.y;
  uint32_t prefix = st[row * 8 + 0];
  uint32_t colbase = blockIdx.x * CHUNK;
  const float4* p = (const float4*)(src + (size_t)row * NN + colbase);
  for (uint32_t j = threadIdx.x; j < CHUNK / 4; j += 256) {
    float4 v = p[j];
    float vv[4] = {v.x, v.y, v.z, v.w};
#pragma unroll
    for (int e = 0; e < 4; ++e) {
      uint32_t key = (SRC == 0) ? key_x(vv[e]) : key_s(vv[e]);
      if ((key >> 21) == prefix) {
        uint32_t idx = atomicAdd(&ccnt[row], 1u);
        if (idx < CAP) cand[row * CAP + idx] = colbase + j * 4 + e;
      }
    }
  }
}

// ---- finish select on compact candidates: bits[20:10], bits[9:0], ties ----
template <int SRC>
__global__ void __launch_bounds__(256)
k_select(const float* __restrict__ src, const uint32_t* __restrict__ cand,
         const uint32_t* __restrict__ ccnt, uint32_t* __restrict__ st,
         uint32_t* __restrict__ sel) {
  __shared__ uint32_t lh[2048];
  __shared__ uint32_t csum[256];
  __shared__ uint32_t tie[1024];
  __shared__ uint32_t sh[8];
  uint32_t row = blockIdx.x;
  uint32_t cnt = ccnt[row]; if (cnt > CAP) cnt = CAP;
  uint32_t prefix = st[row * 8 + 0];
  uint32_t kk1 = KK - st[row * 8 + 1];
  int t = threadIdx.x;
  // pass A: bits[20:10]
  for (uint32_t b = t; b < 2048; b += 256) lh[b] = 0u;
  __syncthreads();
  for (uint32_t j = t; j < cnt; j += 256) {
    float v = src[(size_t)row * NN + cand[row * CAP + j]];
    uint32_t key = (SRC == 0) ? key_x(v) : key_s(v);
    atomicAdd(&lh[(key >> 10) & 2047u], 1u);
  }
  __syncthreads();
  { uint32_t s = 0; for (int j = 0; j < 8; ++j) s += lh[t * 8 + j]; csum[t] = s; }
  __syncthreads();
  if (t == 0) {
    uint32_t acc = 0, b1 = 0;
    for (int c = 255; c >= 0; --c) {
      if (acc + csum[c] >= kk1) {
        for (int b2 = c * 8 + 7; b2 >= c * 8; --b2) {
          uint32_t hv = lh[b2];
          if (acc + hv >= kk1) { b1 = (uint32_t)b2; break; }
          acc += hv;
        }
        break;
      }
      acc += csum[c];
    }
    sh[0] = b1; sh[1] = kk1 - acc;
  }
  __syncthreads();
  uint32_t b1 = sh[0], kk2 = sh[1];
  // pass B: bits[9:0]
  for (uint32_t b = t; b < 1024; b += 256) lh[b] = 0u;
  __syncthreads();
  for (uint32_t j = t; j < cnt; j += 256) {
    float v = src[(size_t)row * NN + cand[row * CAP + j]];
    uint32_t key = (SRC == 0) ? key_x(v) : key_s(v);
    if (((key >> 10) & 2047u) == b1) atomicAdd(&lh[key & 1023u], 1u);
  }
  __syncthreads();
  { uint32_t s = 0; for (int j = 0; j < 4; ++j) s += lh[t * 4 + j]; csum[t] = s; }
  __syncthreads();
  if (t == 0) {
    uint32_t acc = 0, b2f = 0;
    for (int c = 255; c >= 0; --c) {
      if (acc + csum[c] >= kk2) {
        for (int b2 = c * 4 + 3; b2 >= c * 4; --b2) {
          uint32_t hv = lh[b2];
          if (acc + hv >= kk2) { b2f = (uint32_t)b2; break; }
          acc += hv;
        }
        break;
      }
      acc += csum[c];
    }
    sh[2] = (prefix << 21) | (b1 << 10) | b2f;
    sh[3] = kk2 - acc;
    sh[4] = 0u;
  }
  __syncthreads();
  uint32_t thr = sh[2];
  // pass C: collect ties at thr
  for (uint32_t j = t; j < cnt; j += 256) {
    uint32_t col = cand[row * CAP + j];
    float v = src[(size_t)row * NN + col];
    uint32_t key = (SRC == 0) ? key_x(v) : key_s(v);
    if (key == thr) {
      uint32_t idx = atomicAdd(&sh[4], 1u);
      if (idx < 1024) tie[idx] = col;
    }
  }
  __syncthreads();
  uint32_t m = sh[3], tc = sh[4];
  if (tc > 1024) tc = 1024;
  if (m > tc) m = tc;
  if (m > SELCAP) m = SELCAP;
  for (uint32_t a = t; a < tc; a += 256) {
    uint32_t my = tie[a], rank = 0;
    for (uint32_t b = 0; b < tc; ++b) rank += (tie[b] < my) ? 1u : 0u;
    if (rank < m) sel[row * SELCAP + rank] = my;   // lowest-index ties win
  }
  if (t == 0) { st[row * 8 + 2] = thr; st[row * 8 + 4] = m; }
}

// ---- s = log(probs)+gumbel (stage-1 ties inline) + fused stage-2 pass-0 hist ----
__global__ void __launch_bounds__(256)
k_compute_s(const float* __restrict__ x, float* __restrict__ out,
            const uint32_t* __restrict__ st1, const uint32_t* __restrict__ sel1,
            uint32_t* __restrict__ hist) {
  __shared__ uint32_t lh[2048];
  uint32_t row = blockIdx.y;
  for (uint32_t b = threadIdx.x; b < 2048; b += 256) lh[b] = 0u;
  __syncthreads();
  uint32_t thr1 = st1[row * 8 + 2];
  uint32_t m1 = st1[row * 8 + 4];
  float CT = c_top_val(), CR = c_rand_val();
  uint32_t colbase = blockIdx.x * CHUNK;
  const float4* px = (const float4*)(x + (size_t)row * NN + colbase);
  float4* po = (float4*)(out + (size_t)row * NN + colbase);
  for (uint32_t j = threadIdx.x; j < CHUNK / 4; j += 256) {
    float4 v = px[j];
    float vv[4] = {v.x, v.y, v.z, v.w};
    float rr[4];
#pragma unroll
    for (int e = 0; e < 4; ++e) {
      uint32_t col = colbase + j * 4 + e;
      uint32_t key = key_x(vv[e]);
      float c = CR;
      if (key > thr1) c = CT;
      else if (key == thr1) {
        for (uint32_t q = 0; q < m1; ++q)
          if (sel1[row * SELCAP + q] == col) { c = CT; break; }
      }
      float s = c + gumbel_at(row * NN + col);
      rr[e] = s;
      atomicAdd(&lh[key_s(s) >> 21], 1u);
    }
    po[j] = make_float4(rr[0], rr[1], rr[2], rr[3]);
  }
  __syncthreads();
  uint32_t* gh = hist + row * 2048;
  for (uint32_t b = threadIdx.x; b < 2048; b += 256) {
    uint32_t v = lh[b];
    if (v) atomicAdd(&gh[b], v);
  }
}

// ---- final mask apply (stage-2 ties inline) ----
__global__ void __launch_bounds__(256)
k_final(const float* __restrict__ x, float* __restrict__ out,
        const uint32_t* __restrict__ st2, const uint32_t* __restrict__ sel2) {
  uint32_t row = blockIdx.y;
  uint32_t thr2 = st2[row * 8 + 2];
  uint32_t m2 = st2[row * 8 + 4];
  uint32_t colbase = blockIdx.x * CHUNK;
  const float4* px = (const float4*)(x + (size_t)row * NN + colbase);
  float4* po = (float4*)(out + (size_t)row * NN + colbase);
  for (uint32_t j = threadIdx.x; j < CHUNK / 4; j += 256) {
    float4 sv = po[j];
    float4 xv = px[j];
    float ss[4] = {sv.x, sv.y, sv.z, sv.w};
    float xx[4] = {xv.x, xv.y, xv.z, xv.w};
    float rr[4];
#pragma unroll
    for (int e = 0; e < 4; ++e) {
      uint32_t key = key_s(ss[e]);
      float r = 0.0f;
      if (key > thr2) r = xx[e];
      else if (key == thr2) {
        for (uint32_t q = 0; q < m2; ++q)
          if (sel2[row * SELCAP + q] == colbase + j * 4 + e) { r = xx[e]; break; }
      }
      rr[e] = r;
    }
    po[j] = make_float4(rr[0], rr[1], rr[2], rr[3]);
  }
}

extern "C" void kernel_launch(void* const* d_in, const int* in_sizes, int n_in,
                              void* d_out, int out_size, void* d_ws, size_t ws_size,
                              hipStream_t stream) {
  const float* x = (const float*)d_in[0];
  float* out = (float*)d_out;

  uint32_t* w = (uint32_t*)d_ws;
  uint32_t* h0    = w;                     // stage-1 pass-0 hist (32*2048)
  uint32_t* h3    = h0 + HSLOT;            // stage-2 pass-0 hist (fused)
  uint32_t* st1   = h3 + HSLOT;            // 32*8
  uint32_t* st2   = st1 + BB * 8;
  uint32_t* ccnt1 = st2 + BB * 8;          // 32
  uint32_t* ccnt2 = ccnt1 + BB;            // 32
  uint32_t* sel1  = ccnt2 + BB;            // 32*SELCAP
  uint32_t* sel2  = sel1 + BB * SELCAP;
  uint32_t* cand  = sel2 + BB * SELCAP;    // 32*CAP (8 MB, reused by both stages)

  dim3 blk(256), gridF(W, BB), gridR(BB);

  hipMemsetAsync(w, 0, MEMSET_BYTES, stream);   // h0,h3,st1,st2,ccnt1,ccnt2

  // ---- stage 1: select on key_x(|x|) ----
  k_hist0<<<gridF, blk, 0, stream>>>(x, h0);
  k_scan0<<<gridR, blk, 0, stream>>>(h0, st1);
  k_candcoll<0><<<gridF, blk, 0, stream>>>(x, st1, cand, ccnt1);
  k_select<0><<<gridR, blk, 0, stream>>>(x, cand, ccnt1, st1, sel1);

  // ---- s = log(probs)+gumbel, fused stage-2 pass-0 hist ----
  k_compute_s<<<gridF, blk, 0, stream>>>(x, out, st1, sel1, h3);

  // ---- stage 2: select on key_s(s) ----
  k_scan0<<<gridR, blk, 0, stream>>>(h3, st2);
  k_candcoll<1><<<gridF, blk, 0, stream>>>(out, st2, cand, ccnt2);
  k_select<1><<<gridR, blk, 0, stream>>>(out, cand, ccnt2, st2, sel2);

  // ---- apply mask ----
  k_final<<<gridF, blk, 0, stream>>>(x, out, st2, sel2);
}

// Round 6
// 406.226 us; speedup vs baseline: 9.4887x; 9.4887x over previous
//
#include <hip/hip_runtime.h>
#include <stdint.h>

// ---- frozen correctness (validated R3/R4: absmax 0.0) ----
// threefry partitionable (0,i), bits = out0^out1; Cephes log no-FMA, contract off.

static constexpr uint32_t BB = 32;
static constexpr uint32_t NN = 524288;      // 2^19
static constexpr uint32_t KK = 52429;       // max(1, round(0.1*N))
static constexpr uint32_t W = 64;           // workgroups per row (full passes)
static constexpr uint32_t CHUNK = NN / W;   // 8192 elements per WG
static constexpr uint32_t SEGCAP = 1024;    // candidate slots per (row,seg); mean ~410, sd ~20
static constexpr uint32_t CAP = W * SEGCAP; // 65536 per row
static constexpr uint32_t SELCAP = 512;     // boundary-tie selection cap per row
static constexpr uint32_t HSLOT = BB * 2048;
static constexpr size_t MEMSET_BYTES = (size_t)(2 * HSLOT) * 4u;   // h0 + h3 only

// ---------------- XLA CPU f32 log (Cephes/Eigen-3.3, no FMA) ----------------
__device__ __forceinline__ float xla_logf(float xin) {
#pragma clang fp contract(off)
  float x = fmaxf(xin, __uint_as_float(0x00800000u));
  uint32_t bits = __float_as_uint(x);
  float e = (float)((int)(bits >> 23) - 126);
  x = __uint_as_float((bits & 0x807fffffu) | 0x3f000000u);
  bool mlt = x < 0.707106781186547524f;
  float tmp = mlt ? x : 0.0f;
  x = x - 1.0f;
  e = e - (mlt ? 1.0f : 0.0f);
  x = x + tmp;
  float x2 = x * x;
  float x3 = x2 * x;
  float y, y1, y2;
  y  = 7.0376836292E-2f * x + -1.1514610310E-1f;
  y1 = -1.2420140846E-1f * x + 1.4249322787E-1f;
  y2 = 2.0000714765E-1f * x + -2.4999993993E-1f;
  y  = y * x + 1.1676998740E-1f;
  y1 = y1 * x + -1.6668057665E-1f;
  y2 = y2 * x + 3.3333331174E-1f;
  y  = y * x3 + y1;
  y  = y * x3 + y2;
  y  = y * x3;
  y1 = e * -2.12194440e-4f;
  tmp = x2 * 0.5f;
  y = y + y1;
  x = x - tmp;
  y2 = e * 0.693359375f;
  x = x + y;
  x = x + y2;
  return x;
}

__device__ __forceinline__ float c_top_val()  { return xla_logf((float)((1.0 - 0.1) / 52429.0)); }
__device__ __forceinline__ float c_rand_val() { return xla_logf((float)(0.1 / 471859.0)); }

// ---------------- threefry-2x32, key=(0,42), out0^out1 ----------------
__device__ __forceinline__ uint32_t tf_bits(uint32_t i) {
  const uint32_t ks0 = 0u, ks1 = 42u, ks2 = 0x1BD11BDAu ^ 42u;
  uint32_t x0 = 0u + ks0;
  uint32_t x1 = i + ks1;
#define TFR(r) { x0 += x1; x1 = (x1 << (r)) | (x1 >> (32 - (r))); x1 ^= x0; }
  TFR(13) TFR(15) TFR(26) TFR(6)
  x0 += ks1; x1 += ks2 + 1u;
  TFR(17) TFR(29) TFR(16) TFR(24)
  x0 += ks2; x1 += ks0 + 2u;
  TFR(13) TFR(15) TFR(26) TFR(6)
  x0 += ks0; x1 += ks1 + 3u;
  TFR(17) TFR(29) TFR(16) TFR(24)
  x0 += ks1; x1 += ks2 + 4u;
  TFR(13) TFR(15) TFR(26) TFR(6)
  x0 += ks2; x1 += ks0 + 5u;
#undef TFR
  return x0 ^ x1;
}

__device__ __forceinline__ float gumbel_at(uint32_t i) {
  uint32_t b = tf_bits(i);
  float u = __uint_as_float((b >> 9) | 0x3f800000u) - 1.0f;
  u = fmaxf(u, 1.17549435e-38f);
  float nl = -xla_logf(u);
  return -xla_logf(nl);
}

__device__ __forceinline__ uint32_t key_x(float v) { return __float_as_uint(v) & 0x7fffffffu; }
__device__ __forceinline__ uint32_t key_s(float v) {
  uint32_t b = __float_as_uint(v);
  return (b & 0x80000000u) ? ~b : (b | 0x80000000u);
}

// per-row state (8 u32): [0]=p0 prefix(11b) [1]=cnt_gt_prefix [2]=thr [4]=m

// ---- pass-0 histogram of key top-11 bits (LDS-privatized) ----
__global__ void __launch_bounds__(256)
k_hist0(const float* __restrict__ src, uint32_t* __restrict__ hist) {
  __shared__ uint32_t lh[2048];
  uint32_t row = blockIdx.y;
  for (uint32_t b = threadIdx.x; b < 2048; b += 256) lh[b] = 0u;
  __syncthreads();
  const float4* p = (const float4*)(src + (size_t)row * NN + (size_t)blockIdx.x * CHUNK);
  for (uint32_t j = threadIdx.x; j < CHUNK / 4; j += 256) {
    float4 v = p[j];
    float vv[4] = {v.x, v.y, v.z, v.w};
#pragma unroll
    for (int e = 0; e < 4; ++e) atomicAdd(&lh[key_x(vv[e]) >> 21], 1u);
  }
  __syncthreads();
  uint32_t* gh = hist + row * 2048;
  for (uint32_t b = threadIdx.x; b < 2048; b += 256) {
    uint32_t v = lh[b];
    if (v) atomicAdd(&gh[b], v);
  }
}

// ---- find 11-bit prefix bin containing the k-th largest ----
__global__ void __launch_bounds__(256)
k_scan0(const uint32_t* __restrict__ hist, uint32_t* __restrict__ st) {
  __shared__ uint32_t csum[256];
  int row = blockIdx.x;
  const uint32_t* h = hist + row * 2048;
  int t = threadIdx.x;
  uint32_t s = 0;
  for (int j = 0; j < 8; ++j) s += h[t * 8 + j];
  csum[t] = s;
  __syncthreads();
  if (t == 0) {
    uint32_t acc = 0, bin = 0;
    for (int c = 255; c >= 0; --c) {
      if (acc + csum[c] >= KK) {
        for (int b2 = c * 8 + 7; b2 >= c * 8; --b2) {
          uint32_t hv = h[b2];
          if (acc + hv >= KK) { bin = (uint32_t)b2; break; }
          acc += hv;
        }
        break;
      }
      acc += csum[c];
    }
    st[row * 8 + 0] = bin;
    st[row * 8 + 1] = acc;   // strictly greater than prefix bin
  }
}

// ---- collect candidates into per-(row,seg) private slices; NO global atomics ----
template <int SRC>
__global__ void __launch_bounds__(256)
k_candcoll(const float* __restrict__ src, const uint32_t* __restrict__ st,
           uint32_t* __restrict__ cidx, uint32_t* __restrict__ ckey,
           uint32_t* __restrict__ ccnt) {
  __shared__ uint32_t lcnt;
  uint32_t row = blockIdx.y, seg = blockIdx.x;
  if (threadIdx.x == 0) lcnt = 0u;
  __syncthreads();
  uint32_t prefix = st[row * 8 + 0];
  uint32_t colbase = seg * CHUNK;
  uint32_t base = row * CAP + seg * SEGCAP;
  const float4* p = (const float4*)(src + (size_t)row * NN + colbase);
  for (uint32_t j = threadIdx.x; j < CHUNK / 4; j += 256) {
    float4 v = p[j];
    float vv[4] = {v.x, v.y, v.z, v.w};
#pragma unroll
    for (int e = 0; e < 4; ++e) {
      uint32_t key = (SRC == 0) ? key_x(vv[e]) : key_s(vv[e]);
      if ((key >> 21) == prefix) {
        uint32_t li = atomicAdd(&lcnt, 1u);
        if (li < SEGCAP) { cidx[base + li] = colbase + j * 4 + e; ckey[base + li] = key; }
      }
    }
  }
  __syncthreads();
  if (threadIdx.x == 0) ccnt[row * W + seg] = (lcnt < SEGCAP) ? lcnt : SEGCAP;
}

// ---- finish select on compact (key,idx) lists: bits[20:10], bits[9:0], ties ----
__global__ void __launch_bounds__(256)
k_select(const uint32_t* __restrict__ cidx, const uint32_t* __restrict__ ckey,
         const uint32_t* __restrict__ ccnt, uint32_t* __restrict__ st,
         uint32_t* __restrict__ sel) {
  __shared__ uint32_t lh[2048];
  __shared__ uint32_t csum[256];
  __shared__ uint32_t tie[1024];
  __shared__ uint32_t sh[8];
  uint32_t row = blockIdx.x;
  uint32_t prefix = st[row * 8 + 0];
  uint32_t kk1 = KK - st[row * 8 + 1];
  int t = threadIdx.x;
  // pass A: bits[20:10]
  for (uint32_t b = t; b < 2048; b += 256) lh[b] = 0u;
  __syncthreads();
  for (uint32_t seg = 0; seg < W; ++seg) {
    uint32_t cnt = ccnt[row * W + seg], base = row * CAP + seg * SEGCAP;
    for (uint32_t j = t; j < cnt; j += 256)
      atomicAdd(&lh[(ckey[base + j] >> 10) & 2047u], 1u);
  }
  __syncthreads();
  { uint32_t s = 0; for (int j = 0; j < 8; ++j) s += lh[t * 8 + j]; csum[t] = s; }
  __syncthreads();
  if (t == 0) {
    uint32_t acc = 0, b1 = 0;
    for (int c = 255; c >= 0; --c) {
      if (acc + csum[c] >= kk1) {
        for (int b2 = c * 8 + 7; b2 >= c * 8; --b2) {
          uint32_t hv = lh[b2];
          if (acc + hv >= kk1) { b1 = (uint32_t)b2; break; }
          acc += hv;
        }
        break;
      }
      acc += csum[c];
    }
    sh[0] = b1; sh[1] = kk1 - acc;
  }
  __syncthreads();
  uint32_t b1 = sh[0], kk2 = sh[1];
  // pass B: bits[9:0] within b1
  for (uint32_t b = t; b < 1024; b += 256) lh[b] = 0u;
  __syncthreads();
  for (uint32_t seg = 0; seg < W; ++seg) {
    uint32_t cnt = ccnt[row * W + seg], base = row * CAP + seg * SEGCAP;
    for (uint32_t j = t; j < cnt; j += 256) {
      uint32_t key = ckey[base + j];
      if (((key >> 10) & 2047u) == b1) atomicAdd(&lh[key & 1023u], 1u);
    }
  }
  __syncthreads();
  { uint32_t s = 0; for (int j = 0; j < 4; ++j) s += lh[t * 4 + j]; csum[t] = s; }
  __syncthreads();
  if (t == 0) {
    uint32_t acc = 0, b2f = 0;
    for (int c = 255; c >= 0; --c) {
      if (acc + csum[c] >= kk2) {
        for (int b2 = c * 4 + 3; b2 >= c * 4; --b2) {
          uint32_t hv = lh[b2];
          if (acc + hv >= kk2) { b2f = (uint32_t)b2; break; }
          acc += hv;
        }
        break;
      }
      acc += csum[c];
    }
    sh[2] = (prefix << 21) | (b1 << 10) | b2f;
    sh[3] = kk2 - acc;
    sh[4] = 0u;
  }
  __syncthreads();
  uint32_t thr = sh[2];
  // pass C: collect ties at thr (order arbitrary; re-ranked by column below)
  for (uint32_t seg = 0; seg < W; ++seg) {
    uint32_t cnt = ccnt[row * W + seg], base = row * CAP + seg * SEGCAP;
    for (uint32_t j = t; j < cnt; j += 256) {
      if (ckey[base + j] == thr) {
        uint32_t idx = atomicAdd(&sh[4], 1u);
        if (idx < 1024) tie[idx] = cidx[base + j];
      }
    }
  }
  __syncthreads();
  uint32_t m = sh[3], tc = sh[4];
  if (tc > 1024) tc = 1024;
  if (m > tc) m = tc;
  if (m > SELCAP) m = SELCAP;
  for (uint32_t a = t; a < tc; a += 256) {
    uint32_t my = tie[a], rank = 0;
    for (uint32_t b = 0; b < tc; ++b) rank += (tie[b] < my) ? 1u : 0u;
    if (rank < m) sel[row * SELCAP + rank] = my;   // lowest-index ties win
  }
  if (t == 0) { st[row * 8 + 2] = thr; st[row * 8 + 4] = m; }
}

// ---- s = log(probs)+gumbel (stage-1 ties inline) + fused stage-2 pass-0 hist ----
__global__ void __launch_bounds__(256)
k_compute_s(const float* __restrict__ x, float* __restrict__ out,
            const uint32_t* __restrict__ st1, const uint32_t* __restrict__ sel1,
            uint32_t* __restrict__ hist) {
  __shared__ uint32_t lh[2048];
  uint32_t row = blockIdx.y;
  for (uint32_t b = threadIdx.x; b < 2048; b += 256) lh[b] = 0u;
  __syncthreads();
  uint32_t thr1 = st1[row * 8 + 2];
  uint32_t m1 = st1[row * 8 + 4];
  float CT = c_top_val(), CR = c_rand_val();
  uint32_t colbase = blockIdx.x * CHUNK;
  const float4* px = (const float4*)(x + (size_t)row * NN + colbase);
  float4* po = (float4*)(out + (size_t)row * NN + colbase);
  for (uint32_t j = threadIdx.x; j < CHUNK / 4; j += 256) {
    float4 v = px[j];
    float vv[4] = {v.x, v.y, v.z, v.w};
    float rr[4];
#pragma unroll
    for (int e = 0; e < 4; ++e) {
      uint32_t col = colbase + j * 4 + e;
      uint32_t key = key_x(vv[e]);
      float c = CR;
      if (key > thr1) c = CT;
      else if (key == thr1) {
        for (uint32_t q = 0; q < m1; ++q)
          if (sel1[row * SELCAP + q] == col) { c = CT; break; }
      }
      float s = c + gumbel_at(row * NN + col);
      rr[e] = s;
      atomicAdd(&lh[key_s(s) >> 21], 1u);
    }
    po[j] = make_float4(rr[0], rr[1], rr[2], rr[3]);
  }
  __syncthreads();
  uint32_t* gh = hist + row * 2048;
  for (uint32_t b = threadIdx.x; b < 2048; b += 256) {
    uint32_t v = lh[b];
    if (v) atomicAdd(&gh[b], v);
  }
}

// ---- final mask apply (stage-2 ties inline) ----
__global__ void __launch_bounds__(256)
k_final(const float* __restrict__ x, float* __restrict__ out,
        const uint32_t* __restrict__ st2, const uint32_t* __restrict__ sel2) {
  uint32_t row = blockIdx.y;
  uint32_t thr2 = st2[row * 8 + 2];
  uint32_t m2 = st2[row * 8 + 4];
  uint32_t colbase = blockIdx.x * CHUNK;
  const float4* px = (const float4*)(x + (size_t)row * NN + colbase);
  float4* po = (float4*)(out + (size_t)row * NN + colbase);
  for (uint32_t j = threadIdx.x; j < CHUNK / 4; j += 256) {
    float4 sv = po[j];
    float4 xv = px[j];
    float ss[4] = {sv.x, sv.y, sv.z, sv.w};
    float xx[4] = {xv.x, xv.y, xv.z, xv.w};
    float rr[4];
#pragma unroll
    for (int e = 0; e < 4; ++e) {
      uint32_t key = key_s(ss[e]);
      float r = 0.0f;
      if (key > thr2) r = xx[e];
      else if (key == thr2) {
        for (uint32_t q = 0; q < m2; ++q)
          if (sel2[row * SELCAP + q] == colbase + j * 4 + e) { r = xx[e]; break; }
      }
      rr[e] = r;
    }
    po[j] = make_float4(rr[0], rr[1], rr[2], rr[3]);
  }
}

extern "C" void kernel_launch(void* const* d_in, const int* in_sizes, int n_in,
                              void* d_out, int out_size, void* d_ws, size_t ws_size,
                              hipStream_t stream) {
  const float* x = (const float*)d_in[0];
  float* out = (float*)d_out;

  uint32_t* w = (uint32_t*)d_ws;
  uint32_t* h0    = w;                      // stage-1 pass-0 hist (32*2048)
  uint32_t* h3    = h0 + HSLOT;             // stage-2 pass-0 hist (fused)
  uint32_t* st1   = h3 + HSLOT;             // 32*8
  uint32_t* st2   = st1 + BB * 8;
  uint32_t* ccnt1 = st2 + BB * 8;           // 32*W (plain writes)
  uint32_t* ccnt2 = ccnt1 + BB * W;
  uint32_t* sel1  = ccnt2 + BB * W;         // 32*SELCAP
  uint32_t* sel2  = sel1 + BB * SELCAP;
  uint32_t* cidx  = sel2 + BB * SELCAP;     // 32*CAP (8 MB, reused both stages)
  uint32_t* ckey  = cidx + BB * CAP;        // 32*CAP (8 MB)

  dim3 blk(256), gridF(W, BB), gridR(BB);

  hipMemsetAsync(w, 0, MEMSET_BYTES, stream);   // h0 + h3 (must re-zero every replay)

  // ---- stage 1: select on key_x(|x|) ----
  k_hist0<<<gridF, blk, 0, stream>>>(x, h0);
  k_scan0<<<gridR, blk, 0, stream>>>(h0, st1);
  k_candcoll<0><<<gridF, blk, 0, stream>>>(x, st1, cidx, ckey, ccnt1);
  k_select<<<gridR, blk, 0, stream>>>(cidx, ckey, ccnt1, st1, sel1);

  // ---- s = log(probs)+gumbel, fused stage-2 pass-0 hist ----
  k_compute_s<<<gridF, blk, 0, stream>>>(x, out, st1, sel1, h3);

  // ---- stage 2: select on key_s(s) ----
  k_scan0<<<gridR, blk, 0, stream>>>(h3, st2);
  k_candcoll<1><<<gridF, blk, 0, stream>>>(out, st2, cidx, ckey, ccnt2);
  k_select<<<gridR, blk, 0, stream>>>(cidx, ckey, ccnt2, st2, sel2);

  // ---- apply mask ----
  k_final<<<gridF, blk, 0, stream>>>(x, out, st2, sel2);
}

// Round 7
// 325.960 us; speedup vs baseline: 11.8253x; 1.2462x over previous
//
#include <hip/hip_runtime.h>
#include <stdint.h>

// ---- frozen correctness (validated R3/R4/R6: absmax 0.0) ----
// threefry partitionable (0,i), bits = out0^out1; Cephes log no-FMA, contract off.

static constexpr uint32_t BB = 32;
static constexpr uint32_t NN = 524288;      // 2^19
static constexpr uint32_t KK = 52429;       // max(1, round(0.1*N))
static constexpr uint32_t W = 64;           // workgroups per row (full passes)
static constexpr uint32_t CHUNK = NN / W;   // 8192 elements per WG
static constexpr uint32_t SEGCAP = 1024;    // candidate slots per (row,seg); mean ~410, sd ~20
static constexpr uint32_t CAP = W * SEGCAP; // 65536 per row
static constexpr uint32_t SELCAP = 512;     // boundary-tie selection cap per row
static constexpr uint32_t SENT = 0xFFFFFFFFu;  // unreachable key (see analysis)
static constexpr uint32_t HSLOT = BB * 2048;
static constexpr size_t MEMSET_BYTES = (size_t)(2 * HSLOT) * 4u;   // h0 + h3 only

// ---------------- XLA CPU f32 log (Cephes/Eigen-3.3, no FMA) ----------------
__device__ __forceinline__ float xla_logf(float xin) {
#pragma clang fp contract(off)
  float x = fmaxf(xin, __uint_as_float(0x00800000u));
  uint32_t bits = __float_as_uint(x);
  float e = (float)((int)(bits >> 23) - 126);
  x = __uint_as_float((bits & 0x807fffffu) | 0x3f000000u);
  bool mlt = x < 0.707106781186547524f;
  float tmp = mlt ? x : 0.0f;
  x = x - 1.0f;
  e = e - (mlt ? 1.0f : 0.0f);
  x = x + tmp;
  float x2 = x * x;
  float x3 = x2 * x;
  float y, y1, y2;
  y  = 7.0376836292E-2f * x + -1.1514610310E-1f;
  y1 = -1.2420140846E-1f * x + 1.4249322787E-1f;
  y2 = 2.0000714765E-1f * x + -2.4999993993E-1f;
  y  = y * x + 1.1676998740E-1f;
  y1 = y1 * x + -1.6668057665E-1f;
  y2 = y2 * x + 3.3333331174E-1f;
  y  = y * x3 + y1;
  y  = y * x3 + y2;
  y  = y * x3;
  y1 = e * -2.12194440e-4f;
  tmp = x2 * 0.5f;
  y = y + y1;
  x = x - tmp;
  y2 = e * 0.693359375f;
  x = x + y;
  x = x + y2;
  return x;
}

__device__ __forceinline__ float c_top_val()  { return xla_logf((float)((1.0 - 0.1) / 52429.0)); }
__device__ __forceinline__ float c_rand_val() { return xla_logf((float)(0.1 / 471859.0)); }

// ---------------- threefry-2x32, key=(0,42), out0^out1 ----------------
__device__ __forceinline__ uint32_t tf_bits(uint32_t i) {
  const uint32_t ks0 = 0u, ks1 = 42u, ks2 = 0x1BD11BDAu ^ 42u;
  uint32_t x0 = 0u + ks0;
  uint32_t x1 = i + ks1;
#define TFR(r) { x0 += x1; x1 = (x1 << (r)) | (x1 >> (32 - (r))); x1 ^= x0; }
  TFR(13) TFR(15) TFR(26) TFR(6)
  x0 += ks1; x1 += ks2 + 1u;
  TFR(17) TFR(29) TFR(16) TFR(24)
  x0 += ks2; x1 += ks0 + 2u;
  TFR(13) TFR(15) TFR(26) TFR(6)
  x0 += ks0; x1 += ks1 + 3u;
  TFR(17) TFR(29) TFR(16) TFR(24)
  x0 += ks1; x1 += ks2 + 4u;
  TFR(13) TFR(15) TFR(26) TFR(6)
  x0 += ks2; x1 += ks0 + 5u;
#undef TFR
  return x0 ^ x1;
}

__device__ __forceinline__ float gumbel_at(uint32_t i) {
  uint32_t b = tf_bits(i);
  float u = __uint_as_float((b >> 9) | 0x3f800000u) - 1.0f;
  u = fmaxf(u, 1.17549435e-38f);
  float nl = -xla_logf(u);
  return -xla_logf(nl);
}

__device__ __forceinline__ uint32_t key_x(float v) { return __float_as_uint(v) & 0x7fffffffu; }
__device__ __forceinline__ uint32_t key_s(float v) {
  uint32_t b = __float_as_uint(v);
  return (b & 0x80000000u) ? ~b : (b | 0x80000000u);
}

// per-row state (8 u32): [0]=p0 prefix(11b) [1]=cnt_gt_prefix [2]=thr [4]=m

// ---- pass-0 histogram of key top-11 bits (LDS-privatized) ----
__global__ void __launch_bounds__(256)
k_hist0(const float* __restrict__ src, uint32_t* __restrict__ hist) {
  __shared__ uint32_t lh[2048];
  uint32_t row = blockIdx.y;
  for (uint32_t b = threadIdx.x; b < 2048; b += 256) lh[b] = 0u;
  __syncthreads();
  const float4* p = (const float4*)(src + (size_t)row * NN + (size_t)blockIdx.x * CHUNK);
  for (uint32_t j = threadIdx.x; j < CHUNK / 4; j += 256) {
    float4 v = p[j];
    float vv[4] = {v.x, v.y, v.z, v.w};
#pragma unroll
    for (int e = 0; e < 4; ++e) atomicAdd(&lh[key_x(vv[e]) >> 21], 1u);
  }
  __syncthreads();
  uint32_t* gh = hist + row * 2048;
  for (uint32_t b = threadIdx.x; b < 2048; b += 256) {
    uint32_t v = lh[b];
    if (v) atomicAdd(&gh[b], v);
  }
}

// ---- find 11-bit prefix bin containing the k-th largest ----
__global__ void __launch_bounds__(256)
k_scan0(const uint32_t* __restrict__ hist, uint32_t* __restrict__ st) {
  __shared__ uint32_t csum[256];
  int row = blockIdx.x;
  const uint32_t* h = hist + row * 2048;
  int t = threadIdx.x;
  uint32_t s = 0;
  for (int j = 0; j < 8; ++j) s += h[t * 8 + j];
  csum[t] = s;
  __syncthreads();
  if (t == 0) {
    uint32_t acc = 0, bin = 0;
    for (int c = 255; c >= 0; --c) {
      if (acc + csum[c] >= KK) {
        for (int b2 = c * 8 + 7; b2 >= c * 8; --b2) {
          uint32_t hv = h[b2];
          if (acc + hv >= KK) { bin = (uint32_t)b2; break; }
          acc += hv;
        }
        break;
      }
      acc += csum[c];
    }
    st[row * 8 + 0] = bin;
    st[row * 8 + 1] = acc;   // strictly greater than prefix bin
  }
}

// ---- collect candidates into per-(row,seg) slices; sentinel-fill the rest ----
template <int SRC>
__global__ void __launch_bounds__(256)
k_candcoll(const float* __restrict__ src, const uint32_t* __restrict__ st,
           uint32_t* __restrict__ cidx, uint32_t* __restrict__ ckey) {
  __shared__ uint32_t lcnt;
  uint32_t row = blockIdx.y, seg = blockIdx.x;
  if (threadIdx.x == 0) lcnt = 0u;
  __syncthreads();
  uint32_t prefix = st[row * 8 + 0];
  uint32_t colbase = seg * CHUNK;
  uint32_t base = row * CAP + seg * SEGCAP;
  const float4* p = (const float4*)(src + (size_t)row * NN + colbase);
  for (uint32_t j = threadIdx.x; j < CHUNK / 4; j += 256) {
    float4 v = p[j];
    float vv[4] = {v.x, v.y, v.z, v.w};
#pragma unroll
    for (int e = 0; e < 4; ++e) {
      uint32_t key = (SRC == 0) ? key_x(vv[e]) : key_s(vv[e]);
      if ((key >> 21) == prefix) {
        uint32_t li = atomicAdd(&lcnt, 1u);
        if (li < SEGCAP) { cidx[base + li] = colbase + j * 4 + e; ckey[base + li] = key; }
      }
    }
  }
  __syncthreads();
  uint32_t c = (lcnt < SEGCAP) ? lcnt : SEGCAP;
  for (uint32_t j = c + threadIdx.x; j < SEGCAP; j += 256) ckey[base + j] = SENT;
}

// ---- finish select on flat sentinel-padded (key,idx) lists ----
__global__ void __launch_bounds__(256)
k_select(const uint32_t* __restrict__ cidx, const uint32_t* __restrict__ ckey,
         uint32_t* __restrict__ st, uint32_t* __restrict__ sel) {
  __shared__ uint32_t lh[2048];
  __shared__ uint32_t csum[256];
  __shared__ uint32_t tie[1024];
  __shared__ uint32_t sh[8];
  uint32_t row = blockIdx.x;
  uint32_t prefix = st[row * 8 + 0];
  uint32_t kk1 = KK - st[row * 8 + 1];
  int t = threadIdx.x;
  const uint4* pk = (const uint4*)(ckey + row * CAP);
  // pass A: bits[20:10]
  for (uint32_t b = t; b < 2048; b += 256) lh[b] = 0u;
  __syncthreads();
  for (uint32_t j = t; j < CAP / 4; j += 256) {
    uint4 k4 = pk[j];
    uint32_t kk[4] = {k4.x, k4.y, k4.z, k4.w};
#pragma unroll
    for (int e = 0; e < 4; ++e)
      if (kk[e] != SENT) atomicAdd(&lh[(kk[e] >> 10) & 2047u], 1u);
  }
  __syncthreads();
  { uint32_t s = 0; for (int j = 0; j < 8; ++j) s += lh[t * 8 + j]; csum[t] = s; }
  __syncthreads();
  if (t == 0) {
    uint32_t acc = 0, b1 = 0;
    for (int c = 255; c >= 0; --c) {
      if (acc + csum[c] >= kk1) {
        for (int b2 = c * 8 + 7; b2 >= c * 8; --b2) {
          uint32_t hv = lh[b2];
          if (acc + hv >= kk1) { b1 = (uint32_t)b2; break; }
          acc += hv;
        }
        break;
      }
      acc += csum[c];
    }
    sh[0] = b1; sh[1] = kk1 - acc;
  }
  __syncthreads();
  uint32_t b1 = sh[0], kk2 = sh[1];
  // pass B: bits[9:0] within b1
  for (uint32_t b = t; b < 1024; b += 256) lh[b] = 0u;
  __syncthreads();
  for (uint32_t j = t; j < CAP / 4; j += 256) {
    uint4 k4 = pk[j];
    uint32_t kk[4] = {k4.x, k4.y, k4.z, k4.w};
#pragma unroll
    for (int e = 0; e < 4; ++e)
      if (kk[e] != SENT && ((kk[e] >> 10) & 2047u) == b1)
        atomicAdd(&lh[kk[e] & 1023u], 1u);
  }
  __syncthreads();
  { uint32_t s = 0; for (int j = 0; j < 4; ++j) s += lh[t * 4 + j]; csum[t] = s; }
  __syncthreads();
  if (t == 0) {
    uint32_t acc = 0, b2f = 0;
    for (int c = 255; c >= 0; --c) {
      if (acc + csum[c] >= kk2) {
        for (int b2 = c * 4 + 3; b2 >= c * 4; --b2) {
          uint32_t hv = lh[b2];
          if (acc + hv >= kk2) { b2f = (uint32_t)b2; break; }
          acc += hv;
        }
        break;
      }
      acc += csum[c];
    }
    sh[2] = (prefix << 21) | (b1 << 10) | b2f;
    sh[3] = kk2 - acc;
    sh[4] = 0u;
  }
  __syncthreads();
  uint32_t thr = sh[2];
  // pass C: collect ties at thr (order arbitrary; re-ranked by column below)
  for (uint32_t j = t; j < CAP / 4; j += 256) {
    uint4 k4 = pk[j];
    uint32_t kk[4] = {k4.x, k4.y, k4.z, k4.w};
#pragma unroll
    for (int e = 0; e < 4; ++e) {
      if (kk[e] == thr) {
        uint32_t idx = atomicAdd(&sh[4], 1u);
        if (idx < 1024) tie[idx] = cidx[row * CAP + j * 4 + e];
      }
    }
  }
  __syncthreads();
  uint32_t m = sh[3], tc = sh[4];
  if (tc > 1024) tc = 1024;
  if (m > tc) m = tc;
  if (m > SELCAP) m = SELCAP;
  for (uint32_t a = t; a < tc; a += 256) {
    uint32_t my = tie[a], rank = 0;
    for (uint32_t b = 0; b < tc; ++b) rank += (tie[b] < my) ? 1u : 0u;
    if (rank < m) sel[row * SELCAP + rank] = my;   // lowest-index ties win
  }
  if (t == 0) { st[row * 8 + 2] = thr; st[row * 8 + 4] = m; }
}

// ---- s = log(probs)+gumbel (stage-1 ties inline) + fused stage-2 pass-0 hist ----
// 4-replica LDS histogram: lane&3 picks a copy -> ~4x fewer same-address serializations.
__global__ void __launch_bounds__(256)
k_compute_s(const float* __restrict__ x, float* __restrict__ out,
            const uint32_t* __restrict__ st1, const uint32_t* __restrict__ sel1,
            uint32_t* __restrict__ hist) {
  __shared__ uint32_t lh[4 * 2048];
  uint32_t row = blockIdx.y;
  for (uint32_t b = threadIdx.x; b < 4 * 2048; b += 256) lh[b] = 0u;
  __syncthreads();
  uint32_t rep = (threadIdx.x & 3u) * 2048u;
  uint32_t thr1 = st1[row * 8 + 2];
  uint32_t m1 = st1[row * 8 + 4];
  float CT = c_top_val(), CR = c_rand_val();
  uint32_t colbase = blockIdx.x * CHUNK;
  const float4* px = (const float4*)(x + (size_t)row * NN + colbase);
  float4* po = (float4*)(out + (size_t)row * NN + colbase);
  for (uint32_t j = threadIdx.x; j < CHUNK / 4; j += 256) {
    float4 v = px[j];
    float vv[4] = {v.x, v.y, v.z, v.w};
    float rr[4];
#pragma unroll
    for (int e = 0; e < 4; ++e) {
      uint32_t col = colbase + j * 4 + e;
      uint32_t key = key_x(vv[e]);
      float c = CR;
      if (key > thr1) c = CT;
      else if (key == thr1) {
        for (uint32_t q = 0; q < m1; ++q)
          if (sel1[row * SELCAP + q] == col) { c = CT; break; }
      }
      float s = c + gumbel_at(row * NN + col);
      rr[e] = s;
      atomicAdd(&lh[rep + (key_s(s) >> 21)], 1u);
    }
    po[j] = make_float4(rr[0], rr[1], rr[2], rr[3]);
  }
  __syncthreads();
  uint32_t* gh = hist + row * 2048;
  for (uint32_t b = threadIdx.x; b < 2048; b += 256) {
    uint32_t v = lh[b] + lh[2048 + b] + lh[4096 + b] + lh[6144 + b];
    if (v) atomicAdd(&gh[b], v);
  }
}

// ---- final mask apply (stage-2 ties inline) ----
__global__ void __launch_bounds__(256)
k_final(const float* __restrict__ x, float* __restrict__ out,
        const uint32_t* __restrict__ st2, const uint32_t* __restrict__ sel2) {
  uint32_t row = blockIdx.y;
  uint32_t thr2 = st2[row * 8 + 2];
  uint32_t m2 = st2[row * 8 + 4];
  uint32_t colbase = blockIdx.x * CHUNK;
  const float4* px = (const float4*)(x + (size_t)row * NN + colbase);
  float4* po = (float4*)(out + (size_t)row * NN + colbase);
  for (uint32_t j = threadIdx.x; j < CHUNK / 4; j += 256) {
    float4 sv = po[j];
    float4 xv = px[j];
    float ss[4] = {sv.x, sv.y, sv.z, sv.w};
    float xx[4] = {xv.x, xv.y, xv.z, xv.w};
    float rr[4];
#pragma unroll
    for (int e = 0; e < 4; ++e) {
      uint32_t key = key_s(ss[e]);
      float r = 0.0f;
      if (key > thr2) r = xx[e];
      else if (key == thr2) {
        for (uint32_t q = 0; q < m2; ++q)
          if (sel2[row * SELCAP + q] == colbase + j * 4 + e) { r = xx[e]; break; }
      }
      rr[e] = r;
    }
    po[j] = make_float4(rr[0], rr[1], rr[2], rr[3]);
  }
}

extern "C" void kernel_launch(void* const* d_in, const int* in_sizes, int n_in,
                              void* d_out, int out_size, void* d_ws, size_t ws_size,
                              hipStream_t stream) {
  const float* x = (const float*)d_in[0];
  float* out = (float*)d_out;

  uint32_t* w = (uint32_t*)d_ws;
  uint32_t* h0    = w;                      // stage-1 pass-0 hist (32*2048)
  uint32_t* h3    = h0 + HSLOT;             // stage-2 pass-0 hist (fused)
  uint32_t* st1   = h3 + HSLOT;             // 32*8
  uint32_t* st2   = st1 + BB * 8;
  uint32_t* sel1  = st2 + BB * 8;           // 32*SELCAP
  uint32_t* sel2  = sel1 + BB * SELCAP;
  uint32_t* cidx  = sel2 + BB * SELCAP;     // 32*CAP (8 MB, reused both stages)
  uint32_t* ckey  = cidx + BB * CAP;        // 32*CAP (8 MB)

  dim3 blk(256), gridF(W, BB), gridR(BB);

  hipMemsetAsync(w, 0, MEMSET_BYTES, stream);   // h0 + h3 (must re-zero every replay)

  // ---- stage 1: select on key_x(|x|) ----
  k_hist0<<<gridF, blk, 0, stream>>>(x, h0);
  k_scan0<<<gridR, blk, 0, stream>>>(h0, st1);
  k_candcoll<0><<<gridF, blk, 0, stream>>>(x, st1, cidx, ckey);
  k_select<<<gridR, blk, 0, stream>>>(cidx, ckey, st1, sel1);

  // ---- s = log(probs)+gumbel, fused stage-2 pass-0 hist ----
  k_compute_s<<<gridF, blk, 0, stream>>>(x, out, st1, sel1, h3);

  // ---- stage 2: select on key_s(s) ----
  k_scan0<<<gridR, blk, 0, stream>>>(h3, st2);
  k_candcoll<1><<<gridF, blk, 0, stream>>>(out, st2, cidx, ckey);
  k_select<<<gridR, blk, 0, stream>>>(cidx, ckey, st2, sel2);

  // ---- apply mask ----
  k_final<<<gridF, blk, 0, stream>>>(x, out, st2, sel2);
}

// Round 8
// 206.990 us; speedup vs baseline: 18.6219x; 1.5748x over previous
//
#include <hip/hip_runtime.h>
#include <stdint.h>

// ---- frozen correctness (validated R3/R4/R6/R7: absmax 0.0) ----
// threefry partitionable (0,i), bits = out0^out1; Cephes log no-FMA, contract off.

static constexpr uint32_t BB = 32;
static constexpr uint32_t NN = 524288;      // 2^19
static constexpr uint32_t KK = 52429;       // max(1, round(0.1*N))
static constexpr uint32_t W = 64;           // workgroups per row (full passes)
static constexpr uint32_t CHUNK = NN / W;   // 8192 elements per WG
static constexpr uint32_t SEGCAP = 1024;    // candidate slots per (row,seg); mean ~410, sd ~20
static constexpr uint32_t CAP = W * SEGCAP; // 65536 per row
static constexpr uint32_t SELCAP = 512;     // boundary-tie selection cap per row
static constexpr uint32_t SENT = 0xFFFFFFFFu;  // unreachable key (key_x<=0x7FFFFFFF, finite key_s<0xFF800000)
static constexpr uint32_t HSLOT = BB * 2048;
static constexpr size_t MEMSET_BYTES = (size_t)(2 * HSLOT) * 4u;   // h0 + h3 only

// ---------------- XLA CPU f32 log (Cephes/Eigen-3.3, no FMA) ----------------
__device__ __forceinline__ float xla_logf(float xin) {
#pragma clang fp contract(off)
  float x = fmaxf(xin, __uint_as_float(0x00800000u));
  uint32_t bits = __float_as_uint(x);
  float e = (float)((int)(bits >> 23) - 126);
  x = __uint_as_float((bits & 0x807fffffu) | 0x3f000000u);
  bool mlt = x < 0.707106781186547524f;
  float tmp = mlt ? x : 0.0f;
  x = x - 1.0f;
  e = e - (mlt ? 1.0f : 0.0f);
  x = x + tmp;
  float x2 = x * x;
  float x3 = x2 * x;
  float y, y1, y2;
  y  = 7.0376836292E-2f * x + -1.1514610310E-1f;
  y1 = -1.2420140846E-1f * x + 1.4249322787E-1f;
  y2 = 2.0000714765E-1f * x + -2.4999993993E-1f;
  y  = y * x + 1.1676998740E-1f;
  y1 = y1 * x + -1.6668057665E-1f;
  y2 = y2 * x + 3.3333331174E-1f;
  y  = y * x3 + y1;
  y  = y * x3 + y2;
  y  = y * x3;
  y1 = e * -2.12194440e-4f;
  tmp = x2 * 0.5f;
  y = y + y1;
  x = x - tmp;
  y2 = e * 0.693359375f;
  x = x + y;
  x = x + y2;
  return x;
}

__device__ __forceinline__ float c_top_val()  { return xla_logf((float)((1.0 - 0.1) / 52429.0)); }
__device__ __forceinline__ float c_rand_val() { return xla_logf((float)(0.1 / 471859.0)); }

// ---------------- threefry-2x32, key=(0,42), out0^out1 ----------------
__device__ __forceinline__ uint32_t tf_bits(uint32_t i) {
  const uint32_t ks0 = 0u, ks1 = 42u, ks2 = 0x1BD11BDAu ^ 42u;
  uint32_t x0 = 0u + ks0;
  uint32_t x1 = i + ks1;
#define TFR(r) { x0 += x1; x1 = (x1 << (r)) | (x1 >> (32 - (r))); x1 ^= x0; }
  TFR(13) TFR(15) TFR(26) TFR(6)
  x0 += ks1; x1 += ks2 + 1u;
  TFR(17) TFR(29) TFR(16) TFR(24)
  x0 += ks2; x1 += ks0 + 2u;
  TFR(13) TFR(15) TFR(26) TFR(6)
  x0 += ks0; x1 += ks1 + 3u;
  TFR(17) TFR(29) TFR(16) TFR(24)
  x0 += ks1; x1 += ks2 + 4u;
  TFR(13) TFR(15) TFR(26) TFR(6)
  x0 += ks2; x1 += ks0 + 5u;
#undef TFR
  return x0 ^ x1;
}

__device__ __forceinline__ float gumbel_at(uint32_t i) {
  uint32_t b = tf_bits(i);
  float u = __uint_as_float((b >> 9) | 0x3f800000u) - 1.0f;
  u = fmaxf(u, 1.17549435e-38f);
  float nl = -xla_logf(u);
  return -xla_logf(nl);
}

__device__ __forceinline__ uint32_t key_x(float v) { return __float_as_uint(v) & 0x7fffffffu; }
__device__ __forceinline__ uint32_t key_s(float v) {
  uint32_t b = __float_as_uint(v);
  return (b & 0x80000000u) ? ~b : (b | 0x80000000u);
}

// per-row state (8 u32): [0]=p0 prefix(11b) [1]=cnt_gt_prefix [2]=thr [4]=m

// ---- pass-0 histogram of key top-11 bits (LDS-privatized) ----
__global__ void __launch_bounds__(256)
k_hist0(const float* __restrict__ src, uint32_t* __restrict__ hist) {
  __shared__ uint32_t lh[2048];
  uint32_t row = blockIdx.y;
  for (uint32_t b = threadIdx.x; b < 2048; b += 256) lh[b] = 0u;
  __syncthreads();
  const float4* p = (const float4*)(src + (size_t)row * NN + (size_t)blockIdx.x * CHUNK);
  for (uint32_t j = threadIdx.x; j < CHUNK / 4; j += 256) {
    float4 v = p[j];
    float vv[4] = {v.x, v.y, v.z, v.w};
#pragma unroll
    for (int e = 0; e < 4; ++e) atomicAdd(&lh[key_x(vv[e]) >> 21], 1u);
  }
  __syncthreads();
  uint32_t* gh = hist + row * 2048;
  for (uint32_t b = threadIdx.x; b < 2048; b += 256) {
    uint32_t v = lh[b];
    if (v) atomicAdd(&gh[b], v);
  }
}

// ---- find 11-bit prefix bin containing the k-th largest ----
__global__ void __launch_bounds__(256)
k_scan0(const uint32_t* __restrict__ hist, uint32_t* __restrict__ st) {
  __shared__ uint32_t csum[256];
  int row = blockIdx.x;
  const uint32_t* h = hist + row * 2048;
  int t = threadIdx.x;
  uint32_t s = 0;
  for (int j = 0; j < 8; ++j) s += h[t * 8 + j];
  csum[t] = s;
  __syncthreads();
  if (t == 0) {
    uint32_t acc = 0, bin = 0;
    for (int c = 255; c >= 0; --c) {
      if (acc + csum[c] >= KK) {
        for (int b2 = c * 8 + 7; b2 >= c * 8; --b2) {
          uint32_t hv = h[b2];
          if (acc + hv >= KK) { bin = (uint32_t)b2; break; }
          acc += hv;
        }
        break;
      }
      acc += csum[c];
    }
    st[row * 8 + 0] = bin;
    st[row * 8 + 1] = acc;   // strictly greater than prefix bin
  }
}

// ---- collect candidates into per-(row,seg) slices; sentinel-fill the rest ----
template <int SRC>
__global__ void __launch_bounds__(256)
k_candcoll(const float* __restrict__ src, const uint32_t* __restrict__ st,
           uint32_t* __restrict__ cidx, uint32_t* __restrict__ ckey) {
  __shared__ uint32_t lcnt;
  uint32_t row = blockIdx.y, seg = blockIdx.x;
  if (threadIdx.x == 0) lcnt = 0u;
  __syncthreads();
  uint32_t prefix = st[row * 8 + 0];
  uint32_t colbase = seg * CHUNK;
  uint32_t base = row * CAP + seg * SEGCAP;
  const float4* p = (const float4*)(src + (size_t)row * NN + colbase);
  for (uint32_t j = threadIdx.x; j < CHUNK / 4; j += 256) {
    float4 v = p[j];
    float vv[4] = {v.x, v.y, v.z, v.w};
#pragma unroll
    for (int e = 0; e < 4; ++e) {
      uint32_t key = (SRC == 0) ? key_x(vv[e]) : key_s(vv[e]);
      if ((key >> 21) == prefix) {
        uint32_t li = atomicAdd(&lcnt, 1u);
        if (li < SEGCAP) { cidx[base + li] = colbase + j * 4 + e; ckey[base + li] = key; }
      }
    }
  }
  __syncthreads();
  uint32_t c = (lcnt < SEGCAP) ? lcnt : SEGCAP;
  for (uint32_t j = c + threadIdx.x; j < SEGCAP; j += 256) ckey[base + j] = SENT;
}

// ---- finish select: pass A hist bits[20:10] (batched loads), pass B collect
//      matching 22-bit-prefix entries into LDS, exact in-LDS rank for thr/m/sel ----
__global__ void __launch_bounds__(1024)
k_select(const uint32_t* __restrict__ cidx, const uint32_t* __restrict__ ckey,
         uint32_t* __restrict__ st, uint32_t* __restrict__ sel) {
  __shared__ uint32_t lh[2048];
  __shared__ uint32_t csum[256];
  __shared__ uint32_t lkey[1024];
  __shared__ uint32_t lidx[1024];
  __shared__ uint32_t sh[8];
  uint32_t row = blockIdx.x;
  uint32_t prefix = st[row * 8 + 0];
  uint32_t kk1 = KK - st[row * 8 + 1];
  uint32_t t = threadIdx.x;
  const uint4* pk = (const uint4*)(ckey + row * CAP);
  // ---- pass A: hist of bits[20:10], 4 loads in flight ----
  for (uint32_t b = t; b < 2048; b += 1024) lh[b] = 0u;
  __syncthreads();
  for (uint32_t j0 = 0; j0 < CAP / 4; j0 += 4 * 1024) {
    uint4 k4[4];
#pragma unroll
    for (int u = 0; u < 4; ++u) k4[u] = pk[j0 + u * 1024 + t];
#pragma unroll
    for (int u = 0; u < 4; ++u) {
      uint32_t kk[4] = {k4[u].x, k4[u].y, k4[u].z, k4[u].w};
#pragma unroll
      for (int e = 0; e < 4; ++e)
        if (kk[e] != SENT) atomicAdd(&lh[(kk[e] >> 10) & 2047u], 1u);
    }
  }
  __syncthreads();
  if (t < 256) { uint32_t s = 0; for (int j = 0; j < 8; ++j) s += lh[t * 8 + j]; csum[t] = s; }
  __syncthreads();
  if (t == 0) {
    uint32_t acc = 0, b1 = 0;
    for (int c = 255; c >= 0; --c) {
      if (acc + csum[c] >= kk1) {
        for (int b2 = c * 8 + 7; b2 >= c * 8; --b2) {
          uint32_t hv = lh[b2];
          if (acc + hv >= kk1) { b1 = (uint32_t)b2; break; }
          acc += hv;
        }
        break;
      }
      acc += csum[c];
    }
    sh[0] = b1; sh[1] = kk1 - acc; sh[4] = 0u;
  }
  __syncthreads();
  uint32_t b1 = sh[0], kk2 = sh[1];
  uint32_t pfx22 = (prefix << 11) | b1;
  // ---- pass B: collect (key,idx) with 22-bit prefix match into LDS ----
  for (uint32_t j0 = 0; j0 < CAP / 4; j0 += 4 * 1024) {
    uint4 k4[4];
#pragma unroll
    for (int u = 0; u < 4; ++u) k4[u] = pk[j0 + u * 1024 + t];
#pragma unroll
    for (int u = 0; u < 4; ++u) {
      uint32_t kk[4] = {k4[u].x, k4[u].y, k4[u].z, k4[u].w};
#pragma unroll
      for (int e = 0; e < 4; ++e) {
        if ((kk[e] >> 10) == pfx22) {
          uint32_t li = atomicAdd(&sh[4], 1u);
          if (li < 1024) { lkey[li] = kk[e]; lidx[li] = cidx[row * CAP + (j0 + u * 1024 + t) * 4 + e]; }
        }
      }
    }
  }
  __syncthreads();
  uint32_t cnt = sh[4]; if (cnt > 1024) cnt = 1024;
  // ---- exact rank over <=1024 entries: thr, m, tie selection by lowest idx ----
  if (t < cnt) {
    uint32_t myk = lkey[t], myi = lidx[t];
    uint32_t gt = 0, eq = 0, eqlt = 0;
    for (uint32_t b = 0; b < cnt; ++b) {
      uint32_t kb = lkey[b];
      gt += (kb > myk) ? 1u : 0u;
      if (kb == myk) { eq++; eqlt += (lidx[b] < myi) ? 1u : 0u; }
    }
    if (gt < kk2 && gt + eq >= kk2) {          // my key is the threshold
      uint32_t m = kk2 - gt;                   // ties to take (lowest indices)
      if (eqlt == 0) { st[row * 8 + 2] = myk; st[row * 8 + 4] = (m > SELCAP) ? SELCAP : m; }
      if (eqlt < m && eqlt < SELCAP) sel[row * SELCAP + eqlt] = myi;
    }
  }
}

// ---- s = log(probs)+gumbel (stage-1 ties inline) + fused stage-2 pass-0 hist ----
// 4-replica LDS histogram: lane&3 picks a copy -> ~4x fewer same-address serializations.
__global__ void __launch_bounds__(256)
k_compute_s(const float* __restrict__ x, float* __restrict__ out,
            const uint32_t* __restrict__ st1, const uint32_t* __restrict__ sel1,
            uint32_t* __restrict__ hist) {
  __shared__ uint32_t lh[4 * 2048];
  uint32_t row = blockIdx.y;
  for (uint32_t b = threadIdx.x; b < 4 * 2048; b += 256) lh[b] = 0u;
  __syncthreads();
  uint32_t rep = (threadIdx.x & 3u) * 2048u;
  uint32_t thr1 = st1[row * 8 + 2];
  uint32_t m1 = st1[row * 8 + 4];
  float CT = c_top_val(), CR = c_rand_val();
  uint32_t colbase = blockIdx.x * CHUNK;
  const float4* px = (const float4*)(x + (size_t)row * NN + colbase);
  float4* po = (float4*)(out + (size_t)row * NN + colbase);
  for (uint32_t j = threadIdx.x; j < CHUNK / 4; j += 256) {
    float4 v = px[j];
    float vv[4] = {v.x, v.y, v.z, v.w};
    float rr[4];
#pragma unroll
    for (int e = 0; e < 4; ++e) {
      uint32_t col = colbase + j * 4 + e;
      uint32_t key = key_x(vv[e]);
      float c = CR;
      if (key > thr1) c = CT;
      else if (key == thr1) {
        for (uint32_t q = 0; q < m1; ++q)
          if (sel1[row * SELCAP + q] == col) { c = CT; break; }
      }
      float s = c + gumbel_at(row * NN + col);
      rr[e] = s;
      atomicAdd(&lh[rep + (key_s(s) >> 21)], 1u);
    }
    po[j] = make_float4(rr[0], rr[1], rr[2], rr[3]);
  }
  __syncthreads();
  uint32_t* gh = hist + row * 2048;
  for (uint32_t b = threadIdx.x; b < 2048; b += 256) {
    uint32_t v = lh[b] + lh[2048 + b] + lh[4096 + b] + lh[6144 + b];
    if (v) atomicAdd(&gh[b], v);
  }
}

// ---- final mask apply (stage-2 ties inline) ----
__global__ void __launch_bounds__(256)
k_final(const float* __restrict__ x, float* __restrict__ out,
        const uint32_t* __restrict__ st2, const uint32_t* __restrict__ sel2) {
  uint32_t row = blockIdx.y;
  uint32_t thr2 = st2[row * 8 + 2];
  uint32_t m2 = st2[row * 8 + 4];
  uint32_t colbase = blockIdx.x * CHUNK;
  const float4* px = (const float4*)(x + (size_t)row * NN + colbase);
  float4* po = (float4*)(out + (size_t)row * NN + colbase);
  for (uint32_t j = threadIdx.x; j < CHUNK / 4; j += 256) {
    float4 sv = po[j];
    float4 xv = px[j];
    float ss[4] = {sv.x, sv.y, sv.z, sv.w};
    float xx[4] = {xv.x, xv.y, xv.z, xv.w};
    float rr[4];
#pragma unroll
    for (int e = 0; e < 4; ++e) {
      uint32_t key = key_s(ss[e]);
      float r = 0.0f;
      if (key > thr2) r = xx[e];
      else if (key == thr2) {
        for (uint32_t q = 0; q < m2; ++q)
          if (sel2[row * SELCAP + q] == colbase + j * 4 + e) { r = xx[e]; break; }
      }
      rr[e] = r;
    }
    po[j] = make_float4(rr[0], rr[1], rr[2], rr[3]);
  }
}

extern "C" void kernel_launch(void* const* d_in, const int* in_sizes, int n_in,
                              void* d_out, int out_size, void* d_ws, size_t ws_size,
                              hipStream_t stream) {
  const float* x = (const float*)d_in[0];
  float* out = (float*)d_out;

  uint32_t* w = (uint32_t*)d_ws;
  uint32_t* h0    = w;                      // stage-1 pass-0 hist (32*2048)
  uint32_t* h3    = h0 + HSLOT;             // stage-2 pass-0 hist (fused)
  uint32_t* st1   = h3 + HSLOT;             // 32*8
  uint32_t* st2   = st1 + BB * 8;
  uint32_t* sel1  = st2 + BB * 8;           // 32*SELCAP
  uint32_t* sel2  = sel1 + BB * SELCAP;
  uint32_t* cidx  = sel2 + BB * SELCAP;     // 32*CAP (8 MB, reused both stages)
  uint32_t* ckey  = cidx + BB * CAP;        // 32*CAP (8 MB)

  dim3 blk(256), blkS(1024), gridF(W, BB), gridR(BB);

  hipMemsetAsync(w, 0, MEMSET_BYTES, stream);   // h0 + h3 (must re-zero every replay)

  // ---- stage 1: select on key_x(|x|) ----
  k_hist0<<<gridF, blk, 0, stream>>>(x, h0);
  k_scan0<<<gridR, blk, 0, stream>>>(h0, st1);
  k_candcoll<0><<<gridF, blk, 0, stream>>>(x, st1, cidx, ckey);
  k_select<<<gridR, blkS, 0, stream>>>(cidx, ckey, st1, sel1);

  // ---- s = log(probs)+gumbel, fused stage-2 pass-0 hist ----
  k_compute_s<<<gridF, blk, 0, stream>>>(x, out, st1, sel1, h3);

  // ---- stage 2: select on key_s(s) ----
  k_scan0<<<gridR, blk, 0, stream>>>(h3, st2);
  k_candcoll<1><<<gridF, blk, 0, stream>>>(out, st2, cidx, ckey);
  k_select<<<gridR, blkS, 0, stream>>>(cidx, ckey, st2, sel2);

  // ---- apply mask ----
  k_final<<<gridF, blk, 0, stream>>>(x, out, st2, sel2);
}